// Round 6
// baseline (440.001 us; speedup 1.0000x reference)
//
#include <hip/hip_runtime.h>
#include <hip/hip_bf16.h>

// FactorAtt (CoaT) fused pipeline v5, MI355X/gfx950.
// B=8, N=4096, C=768, H=12, D=64.  M_tot = B*N = 32768.
//
// Math: out[b] = q[b] @ M[b] + bp, where
//   Kh = k @ Wk^T (bf16), Vh = v @ Wv^T
//   ctx[b,h,dk,dv] = sum_n softmax_n(Kh)[n,dk] * Vh[n,dv]
//   Gt[b][co][h*64+dk] = sum_dv ctx[b,h,dk,dv] * Wp[co, h*64+dv]
//   Mt[b][co][ci] = sum_kk Gt[b][co][kk] * Wq[kk][ci]
//   out[b][n,co] = sum_ci q[b][n,ci] * Mt[b][co,ci] + bp[co]
// v5: gemm_bt = depth-3 pipeline, counted vmcnt (T4: never drain to 0 in main
// loop), raw s_barrier + per-wave lgkmcnt(0); B/A-bf16 LDS XOR swizzle
// (chunk ^= (row>>1)&3) both-sides to kill the 8-way frag-read conflict;
// K+V projections merged into one z=2 launch.

typedef __bf16 bf16x8 __attribute__((ext_vector_type(8)));
typedef __bf16 bf16x4 __attribute__((ext_vector_type(4)));
typedef float f32x4 __attribute__((ext_vector_type(4)));

#define GLOAD_LDS16(g, l)                                                        \
  __builtin_amdgcn_global_load_lds(                                              \
      (const __attribute__((address_space(1))) void*)(g),                        \
      (__attribute__((address_space(3))) void*)(l), 16, 0, 0)

__device__ __forceinline__ float bf2f(__hip_bfloat16 h) { return __bfloat162float(h); }

// ---------------------------------------------------------------- cast fp32->bf16
__global__ void cast_kernel(const float* __restrict__ src,
                            __bf16* __restrict__ dst, long n) {
  long i = ((long)blockIdx.x * blockDim.x + threadIdx.x) * 4;
  if (i + 3 < n) {
    const float4 f = *(const float4*)(src + i);
    bf16x4 u = {(__bf16)f.x, (__bf16)f.y, (__bf16)f.z, (__bf16)f.w};
    *(bf16x4*)(dst + i) = u;
  }
}

// ---------------------------------------------------------------- transpose cast
// dst[ci][kk] = src[kk][ci]  (768x768, fp32 -> bf16)
__global__ void transpose_cast(const float* __restrict__ src,
                               __bf16* __restrict__ dst) {
  __shared__ float tile[32][33];
  const int bx = blockIdx.x * 32, by = blockIdx.y * 32;
  const int tx = threadIdx.x, ty = threadIdx.y;  // 32 x 8
#pragma unroll
  for (int j = 0; j < 32; j += 8)
    tile[ty + j][tx] = src[(long)(bx + ty + j) * 768 + by + tx];
  __syncthreads();
#pragma unroll
  for (int j = 0; j < 32; j += 8)
    dst[(long)(by + ty + j) * 768 + bx + tx] = (__bf16)tile[tx][ty + j];
}

// ---------------------------------------------------------------- GEMM (B^T form)
// out[m,n] = sum_k A[m,k] * Bt[n,k];  K=768, tiles 128x128, BK=32, 4 waves.
// Depth-3 LDS pipeline with counted vmcnt; XOR-swizzled bf16 tiles.
// A2 != nullptr: z==1 selects A2 as the A matrix (z-stride disabled).
template <bool AF32>
__global__ __launch_bounds__(256, 2)
void gemm_bt(const void* __restrict__ Abase_, const void* __restrict__ A2,
             const __bf16* __restrict__ Btbase,
             __bf16* __restrict__ outBbase,
             float* __restrict__ outF,
             const float* __restrict__ bias,
             long sAz, long sBz, long sOz, long sBbatch) {
  constexpr int K = 768;
  constexpr int NT = K / 32;      // 24 K-tiles
  constexpr int LDSB = 128 * 32;  // elements per tile buffer
  const int tid = threadIdx.x;
  const int lane = tid & 63;
  const int w = tid >> 6;
  const int wr = (w >> 1) * 64;
  const int wc = (w & 1) * 64;

  // bijective XCD-chunked swizzle (m204)
  long flat = ((long)blockIdx.z * gridDim.y + blockIdx.y) * gridDim.x + blockIdx.x;
  const long total = (long)gridDim.x * gridDim.y * gridDim.z;
  if ((total & 7) == 0) {
    flat = (flat & 7) * (total >> 3) + (flat >> 3);
  }
  const int bx = (int)(flat % gridDim.x);
  const long rem = flat / gridDim.x;
  const int by = (int)(rem % gridDim.y);
  const int bz = (int)(rem / gridDim.y);

  const int z = bz;
  const int m0 = by * 128;
  const int n0 = bx * 128;

  const __bf16* Bt = Btbase + (long)z * sBz + (long)(m0 >> 12) * sBbatch;

  // triple buffers
  __shared__ __align__(16) float AsF[AF32 ? 3 * LDSB : 8];
  __shared__ __align__(16) __bf16 AsB[AF32 ? 8 : 3 * LDSB];
  __shared__ __align__(16) __bf16 Bs[3 * LDSB];

  f32x4 acc[4][4] = {};

  // ---- staging setup (bf16 tiles: rows 64B = 4 x 16B chunks)
  // XOR swizzle: phys chunk pc holds logical chunk pc ^ ((row>>1)&3).
  const int srow = w * 16 + (lane >> 2);              // staged row (and +64)
  const int bkey = (srow >> 1) & 3;                   // same for srow and srow+64
  const int c_logB = (lane & 3) ^ bkey;               // logical chunk to fetch
  const __bf16* gB = Bt + (long)(n0 + srow) * K + c_logB * 8;

  // A fp32 tile: rows 128B = 8 x 16B chunks; phys chunk = logical ^ (row&7)
  const int sr8 = lane >> 3;                          // row&7 within 8-row group
  const int c_logA32 = (lane & 7) ^ sr8;
  const float* gAf = nullptr;
  const __bf16* gAb = nullptr;
  {
    const void* Asel = (A2 != nullptr && z == 1) ? A2 : Abase_;
    const long az = (A2 == nullptr) ? (long)z * sAz : 0;
    if constexpr (AF32) {
      gAf = (const float*)Asel + az + (long)(m0 + w * 8 + sr8) * K + c_logA32 * 4;
    } else {
      gAb = (const __bf16*)Asel + az + (long)(m0 + srow) * K + c_logB * 8;
    }
  }

  const int kseg = (lane >> 4) * 8;  // frag logical k-offset (elements)
  const int rsel = lane & 15;
  const int r7 = rsel & 7;

  auto STAGE = [&](int bo, int k0) {
    if constexpr (AF32) {
      float* l = &AsF[bo + (w * 8) * 32];
#pragma unroll
      for (int p = 0; p < 4; ++p)
        GLOAD_LDS16(gAf + k0 + (long)p * 32 * K, l + p * 32 * 32);
    } else {
      __bf16* l = &AsB[bo + (w * 16) * 32];
      GLOAD_LDS16(gAb + k0, l);
      GLOAD_LDS16(gAb + (long)64 * K + k0, l + 64 * 32);
    }
    __bf16* lB = &Bs[bo + (w * 16) * 32];
    GLOAD_LDS16(gB + k0, lB);
    GLOAD_LDS16(gB + (long)64 * K + k0, lB + 64 * 32);
  };

  auto COMPUTE = [&](int bo) {
    bf16x8 af[4], bfr[4];
#pragma unroll
    for (int i = 0; i < 4; ++i) {
      const int row = wr + i * 16 + rsel;
      if (AF32) {
        const int c0 = (lane >> 4) * 2;  // logical 16B chunk (even)
        const f32x4 lo = *(const f32x4*)&AsF[bo + row * 32 + ((c0 ^ r7) << 2)];
        const f32x4 hi = *(const f32x4*)&AsF[bo + row * 32 + (((c0 + 1) ^ r7) << 2)];
        bf16x8 a = {(__bf16)lo[0], (__bf16)lo[1], (__bf16)lo[2], (__bf16)lo[3],
                    (__bf16)hi[0], (__bf16)hi[1], (__bf16)hi[2], (__bf16)hi[3]};
        af[i] = a;
      } else {
        const int ka = (lane >> 4) ^ ((row >> 1) & 3);
        af[i] = *(const bf16x8*)&AsB[bo + row * 32 + ka * 8];
      }
      const int rowb = wc + i * 16 + rsel;
      const int kb = (lane >> 4) ^ ((rowb >> 1) & 3);
      bfr[i] = *(const bf16x8*)&Bs[bo + rowb * 32 + kb * 8];
    }
#pragma unroll
    for (int i = 0; i < 4; ++i)
#pragma unroll
      for (int j = 0; j < 4; ++j)
        acc[i][j] = __builtin_amdgcn_mfma_f32_16x16x32_bf16(af[i], bfr[j], acc[i][j], 0, 0, 0);
  };

  // Depth-3 pipeline.  L = loads/wave/tile (AF32: 6, bf16: 4).
  // Main loop: stage tile t+2, wait vmcnt(2L) -> tile t complete, tiles
  // t+1/t+2 stay in flight across the barrier (T4).  barrier#1: all waves'
  // tile-t loads done.  barrier#2 (after lgkmcnt(0)): all waves done reading
  // buf[t%3], safe to re-stage it next iteration ((t+3)%3 == t%3).
  STAGE(0, 0);
  STAGE(LDSB, 32);
#pragma unroll 1
  for (int t = 0; t < NT; ++t) {
    const int ks = (t + 2) * 32;
    if (ks < K) {
      STAGE(((t + 2) % 3) * LDSB, ks);
      if constexpr (AF32) asm volatile("s_waitcnt vmcnt(12)" ::: "memory");
      else                asm volatile("s_waitcnt vmcnt(8)" ::: "memory");
    } else if (t == NT - 2) {
      if constexpr (AF32) asm volatile("s_waitcnt vmcnt(6)" ::: "memory");
      else                asm volatile("s_waitcnt vmcnt(4)" ::: "memory");
    } else {
      asm volatile("s_waitcnt vmcnt(0)" ::: "memory");
    }
    __builtin_amdgcn_sched_barrier(0);
    __builtin_amdgcn_s_barrier();
    COMPUTE((t % 3) * LDSB);
    asm volatile("s_waitcnt lgkmcnt(0)" ::: "memory");
    __builtin_amdgcn_sched_barrier(0);
    __builtin_amdgcn_s_barrier();
  }

  // C/D layout (m89): col = lane&15, row = (lane>>4)*4 + r
  const int r0 = (lane >> 4) * 4;
  if (outF == nullptr) {
    __bf16* outp = outBbase + (long)z * sOz;
#pragma unroll
    for (int i = 0; i < 4; ++i) {
      const int row = m0 + wr + i * 16 + r0;
#pragma unroll
      for (int j = 0; j < 4; ++j) {
        const int col = n0 + wc + j * 16 + rsel;
#pragma unroll
        for (int r = 0; r < 4; ++r)
          outp[(long)(row + r) * 768 + col] = (__bf16)acc[i][j][r];
      }
    }
  } else {
#pragma unroll
    for (int i = 0; i < 4; ++i) {
      const int row = m0 + wr + i * 16 + r0;
#pragma unroll
      for (int j = 0; j < 4; ++j) {
        const int col = n0 + wc + j * 16 + rsel;
        const float bv = bias[col];
#pragma unroll
        for (int r = 0; r < 4; ++r)
          outF[(long)(row + r) * 768 + col] = acc[i][j][r] + bv;
      }
    }
  }
}

// ---------------------------------------------------------------- ctx partials
__global__ __launch_bounds__(256)
void ctx_partial(const __hip_bfloat16* __restrict__ Kh,
                 const __hip_bfloat16* __restrict__ Vh,
                 float* __restrict__ Upart, float* __restrict__ Spart) {
  const int bh = blockIdx.y, chunk = blockIdx.x;
  const int b = bh / 12, h = bh % 12;
  const int t = threadIdx.x;
  const int rr = t >> 6, d = t & 63;
  const int tdk = (t & 15) * 4, tdv = (t >> 4) * 4;
  __shared__ float ek[4][64];
  __shared__ float vv[4][64];
  __shared__ float sred[256];
  f32x4 U[4] = {};
  float myS = 0.f;
  const long base = ((long)b * 4096 + (long)chunk * 512) * 768 + h * 64 + d;
  for (int r4 = 0; r4 < 128; ++r4) {
    const long off = base + (long)(r4 * 4 + rr) * 768;
    const float e = __expf(bf2f(Kh[off]));
    ek[rr][d] = e;
    myS += e;
    vv[rr][d] = bf2f(Vh[off]);
    __syncthreads();
#pragma unroll
    for (int q = 0; q < 4; ++q) {
      const f32x4 a = *(const f32x4*)&ek[q][tdk];
      const f32x4 vx = *(const f32x4*)&vv[q][tdv];
      U[0] += a[0] * vx;
      U[1] += a[1] * vx;
      U[2] += a[2] * vx;
      U[3] += a[3] * vx;
    }
    __syncthreads();
  }
  float* Ub = Upart + (long)(bh * 8 + chunk) * 4096;
#pragma unroll
  for (int i = 0; i < 4; ++i) *(f32x4*)&Ub[(tdk + i) * 64 + tdv] = U[i];
  sred[t] = myS;
  __syncthreads();
  if (t < 64) {
    const float s = sred[t] + sred[t + 64] + sred[t + 128] + sred[t + 192];
    Spart[(long)(bh * 8 + chunk) * 64 + t] = s;
  }
}

__global__ __launch_bounds__(256)
void ctx_reduce(const float* __restrict__ Upart, const float* __restrict__ Spart,
                float* __restrict__ ctx) {
  const int bh = blockIdx.x;
  const int t = threadIdx.x;
  const int tdk = (t & 15) * 4, tdv = (t >> 4) * 4;
  __shared__ float S[64];
  if (t < 64) {
    float s = 0.f;
#pragma unroll
    for (int c = 0; c < 8; ++c) s += Spart[(long)(bh * 8 + c) * 64 + t];
    S[t] = s;
  }
  __syncthreads();
#pragma unroll
  for (int i = 0; i < 4; ++i) {
    const int dk = tdk + i;
    f32x4 u = {};
#pragma unroll
    for (int c = 0; c < 8; ++c)
      u += *(const f32x4*)&Upart[(long)(bh * 8 + c) * 4096 + dk * 64 + tdv];
    u *= (1.f / S[dk]);
    *(f32x4*)&ctx[(long)bh * 4096 + dk * 64 + tdv] = u;
  }
}

// ---------------------------------------------------------------- G matrix
// Gt[b][co][h*64+dk] = sum_dv ctx[b,h,dk,dv] * Wp[co, h*64+dv]   (bf16 out)
__global__ __launch_bounds__(256, 2)
void gstack(const float* __restrict__ ctx, const float* __restrict__ Wp,
            __bf16* __restrict__ Gt) {
  const int cc = blockIdx.x, h = blockIdx.y, b = blockIdx.z;
  const int t = threadIdx.x, lane = t & 63, w = t >> 6;
  const int co0 = cc * 192;
  __shared__ __align__(16) float wf[192 * 64];  // 48 KB

#pragma unroll
  for (int i = 0; i < 12; ++i) {
    const int flat = i * 256 + t;
    const int r = flat >> 4, c4 = flat & 15;
    const f32x4 vsrc = *(const f32x4*)&Wp[(long)(co0 + r) * 768 + h * 64 + c4 * 4];
    *(f32x4*)&wf[r * 64 + c4 * 4] = vsrc;
  }

  f32x4 cx[16];
  const float* crow = ctx + ((long)(b * 12 + h) * 64 + lane) * 64;
#pragma unroll
  for (int j = 0; j < 16; ++j) cx[j] = *(const f32x4*)&crow[j * 4];

  __syncthreads();

  __bf16* gout = Gt + ((long)(b * 768 + co0 + w * 48) * 768) + h * 64 + lane;
  for (int co = 0; co < 48; ++co) {
    const float* wrow = &wf[(w * 48 + co) * 64];
    f32x4 acc = {};
#pragma unroll
    for (int j = 0; j < 16; ++j) acc += cx[j] * *(const f32x4*)&wrow[j * 4];
    const float s = acc[0] + acc[1] + acc[2] + acc[3];
    gout[(long)co * 768] = (__bf16)s;
  }
}

// ---------------------------------------------------------------- launch
extern "C" void kernel_launch(void* const* d_in, const int* in_sizes, int n_in,
                              void* d_out, int out_size, void* d_ws, size_t ws_size,
                              hipStream_t stream) {
  (void)in_sizes; (void)n_in; (void)out_size; (void)ws_size;
  const float* q = (const float*)d_in[0];
  const float* k = (const float*)d_in[1];
  const float* v = (const float*)d_in[2];
  const float* Wq = (const float*)d_in[3];
  const float* Wk = (const float*)d_in[4];
  const float* Wv = (const float*)d_in[5];
  const float* Wp = (const float*)d_in[6];
  const float* bp = (const float*)d_in[7];
  float* out = (float*)d_out;

  const long XE = 32768L * 768L;
  const long WE = 768L * 768L;

  char* ws = (char*)d_ws;
  __bf16* Khb = (__bf16*)ws;                             // XE bf16
  __bf16* Vhb = Khb + XE;                                // XE bf16
  __bf16* Wb = Vhb + XE;                                 // 4*WE bf16: Wk,Wv,(unused),WqT
  __bf16* Gt = Wb + 4 * WE;                              // 8*WE bf16
  __bf16* Mt = Gt + 8 * WE;                              // 8*WE bf16
  float* Upart = (float*)(Mt + 8 * WE);                  // 96*8*4096 f32
  float* Spart = Upart + 96L * 8 * 4096;                 // 96*8*64 f32
  float* ctx = Spart + 96L * 8 * 64;                     // 96*4096 f32

  // 1) weight casts (tiny)
  cast_kernel<<<576, 256, 0, stream>>>(Wk, Wb + 0 * WE, WE);
  cast_kernel<<<576, 256, 0, stream>>>(Wv, Wb + 1 * WE, WE);
  transpose_cast<<<dim3(24, 24), dim3(32, 8), 0, stream>>>(Wq, Wb + 3 * WE);  // WqT

  // 2) K/V projections merged (z=2): z=0 -> Kh = k@Wk^T, z=1 -> Vh = v@Wv^T
  gemm_bt<true><<<dim3(6, 256, 2), 256, 0, stream>>>(k, v, Wb, Khb, nullptr,
                                                     nullptr, 0, WE, XE, 0);

  // 3) softmax-weighted context
  ctx_partial<<<dim3(8, 96), 256, 0, stream>>>((const __hip_bfloat16*)Khb,
                                               (const __hip_bfloat16*)Vhb, Upart, Spart);
  ctx_reduce<<<96, 256, 0, stream>>>(Upart, Spart, ctx);

  // 4) Gt[b] = (ctx @ Wp-blocks)^T   (bf16, per batch; fp32 Wp direct)
  gstack<<<dim3(4, 12, 8), 256, 0, stream>>>(ctx, Wp, Gt);

  // 5) Mt[b] : out[m=co, n=ci] = sum_k Gt[co,k] * WqT[ci,k]
  gemm_bt<false><<<dim3(6, 6, 8), 256, 0, stream>>>(Gt, nullptr, Wb + 3 * WE, Mt,
                                                    nullptr, nullptr, WE, 0, WE, 0);

  // 6) out[b] = q[b] @ Mt[b]^T + bp  (fp32 A direct, fp32 out)
  gemm_bt<true><<<dim3(6, 256, 1), 256, 0, stream>>>(q, nullptr, Mt, nullptr, out,
                                                     bp, 0, 0, 0, WE);
}

// Round 7
// 377.282 us; speedup vs baseline: 1.1662x; 1.1662x over previous
//
#include <hip/hip_runtime.h>
#include <hip/hip_bf16.h>

// FactorAtt (CoaT) fused pipeline v6, MI355X/gfx950.
// B=8, N=4096, C=768, H=12, D=64.  M_tot = B*N = 32768.
//
// Math: out[b] = q[b] @ M[b] + bp, where
//   Kh = k @ Wk^T (bf16), Vh = v @ Wv^T
//   ctx[b,h,dk,dv] = sum_n softmax_n(Kh)[n,dk] * Vh[n,dv]
//   Gt[b][co][h*64+dk] = sum_dv ctx[b,h,dk,dv] * Wp[co, h*64+dv]
//   Mt[b][co][ci] = sum_kk Gt[b][co][kk] * Wq[kk][ci]
//   out[b][n,co] = sum_ci q[b][n,ci] * Mt[b][co,ci] + bp[co]
// v6: REVERT GEMM to v1's proven m97-structure (pure bf16, single 16KB
// buffer, 2 barriers/K-step, 592 TF measured on this problem). Explicit
// fp32->bf16 casts for k,v,q (one z=3 dispatch). AF32 fused staging and
// deep pipelines removed (v4/v5 post-mortem: both regressed).

typedef __bf16 bf16x8 __attribute__((ext_vector_type(8)));
typedef __bf16 bf16x4 __attribute__((ext_vector_type(4)));
typedef float f32x4 __attribute__((ext_vector_type(4)));

#define GLOAD_LDS16(g, l)                                                        \
  __builtin_amdgcn_global_load_lds(                                              \
      (const __attribute__((address_space(1))) void*)(g),                        \
      (__attribute__((address_space(3))) void*)(l), 16, 0, 0)

__device__ __forceinline__ float bf2f(__hip_bfloat16 h) { return __bfloat162float(h); }

// ---------------------------------------------------------------- casts
__global__ void cast_kernel(const float* __restrict__ src,
                            __bf16* __restrict__ dst, long n) {
  long i = ((long)blockIdx.x * blockDim.x + threadIdx.x) * 4;
  if (i + 3 < n) {
    const float4 f = *(const float4*)(src + i);
    bf16x4 u = {(__bf16)f.x, (__bf16)f.y, (__bf16)f.z, (__bf16)f.w};
    *(bf16x4*)(dst + i) = u;
  }
}

// three tensors of exactly XE elements each (XE = 24576*1024)
__global__ void cast3_kernel(const float* __restrict__ s0, const float* __restrict__ s1,
                             const float* __restrict__ s2,
                             __bf16* __restrict__ d0, __bf16* __restrict__ d1,
                             __bf16* __restrict__ d2) {
  const float* src = blockIdx.y == 0 ? s0 : (blockIdx.y == 1 ? s1 : s2);
  __bf16* dst = blockIdx.y == 0 ? d0 : (blockIdx.y == 1 ? d1 : d2);
  const long i = ((long)blockIdx.x * blockDim.x + threadIdx.x) * 4;
  const float4 f = *(const float4*)(src + i);
  bf16x4 u = {(__bf16)f.x, (__bf16)f.y, (__bf16)f.z, (__bf16)f.w};
  *(bf16x4*)(dst + i) = u;
}

// dst[ci][kk] = src[kk][ci]  (768x768, fp32 -> bf16)
__global__ void transpose_cast(const float* __restrict__ src,
                               __bf16* __restrict__ dst) {
  __shared__ float tile[32][33];
  const int bx = blockIdx.x * 32, by = blockIdx.y * 32;
  const int tx = threadIdx.x, ty = threadIdx.y;  // 32 x 8
#pragma unroll
  for (int j = 0; j < 32; j += 8)
    tile[ty + j][tx] = src[(long)(bx + ty + j) * 768 + by + tx];
  __syncthreads();
#pragma unroll
  for (int j = 0; j < 32; j += 8)
    dst[(long)(by + ty + j) * 768 + bx + tx] = (__bf16)tile[tx][ty + j];
}

// ---------------------------------------------------------------- GEMM (B^T form)
// out[m,n] = sum_k A[m,k] * Bt[n,k];  K=768, tiles 128x128, BK=32, 4 waves.
// v1 structure: single 8KB+8KB LDS buffer, global_load_lds w=16, 2 barriers
// per K-step.  z-batched: A += z*sAz, Bt += z*sBz, outB += z*sOz.
// outF mode: fp32 out + bias, Bt additionally batched per 4096 rows (sBbatch).
__global__ __launch_bounds__(256, 2)
void gemm_bt(const __bf16* __restrict__ Abase,
             const __bf16* __restrict__ Btbase,
             __bf16* __restrict__ outBbase,
             float* __restrict__ outF,
             const float* __restrict__ bias,
             long sAz, long sBz, long sOz, long sBbatch) {
  constexpr int K = 768;
  const int tid = threadIdx.x;
  const int lane = tid & 63;
  const int w = tid >> 6;
  const int wr = (w >> 1) * 64;
  const int wc = (w & 1) * 64;

  // bijective XCD-chunked swizzle (m204)
  long flat = ((long)blockIdx.z * gridDim.y + blockIdx.y) * gridDim.x + blockIdx.x;
  const long total = (long)gridDim.x * gridDim.y * gridDim.z;
  if ((total & 7) == 0) {
    flat = (flat & 7) * (total >> 3) + (flat >> 3);
  }
  const int bx = (int)(flat % gridDim.x);
  const long rem = flat / gridDim.x;
  const int by = (int)(rem % gridDim.y);
  const int bz = (int)(rem / gridDim.y);

  const int z = bz;
  const int m0 = by * 128;
  const int n0 = bx * 128;

  const __bf16* A = Abase + (long)z * sAz;
  const __bf16* Bt = Btbase + (long)z * sBz + (long)(m0 >> 12) * sBbatch;

  __shared__ __align__(16) __bf16 As[128 * 32];
  __shared__ __align__(16) __bf16 Bs[128 * 32];

  f32x4 acc[4][4] = {};

  // staging: wave w covers rows w*16..+15 (and +64); lane: row=lane>>2, chunk=lane&3
  const int srow = w * 16 + (lane >> 2);
  const int scol = (lane & 3) * 8;
  const __bf16* gA = A + (long)(m0 + srow) * K + scol;
  const __bf16* gB = Bt + (long)(n0 + srow) * K + scol;
  __bf16* lA = &As[(w * 16) * 32];
  __bf16* lB = &Bs[(w * 16) * 32];

  const int kseg = (lane >> 4) * 8;
  const int rsel = lane & 15;

  for (int k0 = 0; k0 < K; k0 += 32) {
    GLOAD_LDS16(gA + k0, lA);
    GLOAD_LDS16(gA + (long)64 * K + k0, lA + 64 * 32);
    GLOAD_LDS16(gB + k0, lB);
    GLOAD_LDS16(gB + (long)64 * K + k0, lB + 64 * 32);
    __syncthreads();

    bf16x8 af[4], bfr[4];
#pragma unroll
    for (int i = 0; i < 4; ++i) {
      af[i] = *(const bf16x8*)&As[(wr + i * 16 + rsel) * 32 + kseg];
      bfr[i] = *(const bf16x8*)&Bs[(wc + i * 16 + rsel) * 32 + kseg];
    }
#pragma unroll
    for (int i = 0; i < 4; ++i)
#pragma unroll
      for (int j = 0; j < 4; ++j)
        acc[i][j] = __builtin_amdgcn_mfma_f32_16x16x32_bf16(af[i], bfr[j], acc[i][j], 0, 0, 0);
    __syncthreads();
  }

  // C/D layout (m89): col = lane&15, row = (lane>>4)*4 + r
  const int r0 = (lane >> 4) * 4;
  if (outF == nullptr) {
    __bf16* outp = outBbase + (long)z * sOz;
#pragma unroll
    for (int i = 0; i < 4; ++i) {
      const int row = m0 + wr + i * 16 + r0;
#pragma unroll
      for (int j = 0; j < 4; ++j) {
        const int col = n0 + wc + j * 16 + rsel;
#pragma unroll
        for (int r = 0; r < 4; ++r)
          outp[(long)(row + r) * 768 + col] = (__bf16)acc[i][j][r];
      }
    }
  } else {
#pragma unroll
    for (int i = 0; i < 4; ++i) {
      const int row = m0 + wr + i * 16 + r0;
#pragma unroll
      for (int j = 0; j < 4; ++j) {
        const int col = n0 + wc + j * 16 + rsel;
        const float bv = bias[col];
#pragma unroll
        for (int r = 0; r < 4; ++r)
          outF[(long)(row + r) * 768 + col] = acc[i][j][r] + bv;
      }
    }
  }
}

// ---------------------------------------------------------------- ctx partials
__global__ __launch_bounds__(256)
void ctx_partial(const __hip_bfloat16* __restrict__ Kh,
                 const __hip_bfloat16* __restrict__ Vh,
                 float* __restrict__ Upart, float* __restrict__ Spart) {
  const int bh = blockIdx.y, chunk = blockIdx.x;
  const int b = bh / 12, h = bh % 12;
  const int t = threadIdx.x;
  const int rr = t >> 6, d = t & 63;
  const int tdk = (t & 15) * 4, tdv = (t >> 4) * 4;
  __shared__ float ek[4][64];
  __shared__ float vv[4][64];
  __shared__ float sred[256];
  f32x4 U[4] = {};
  float myS = 0.f;
  const long base = ((long)b * 4096 + (long)chunk * 512) * 768 + h * 64 + d;
  for (int r4 = 0; r4 < 128; ++r4) {
    const long off = base + (long)(r4 * 4 + rr) * 768;
    const float e = __expf(bf2f(Kh[off]));
    ek[rr][d] = e;
    myS += e;
    vv[rr][d] = bf2f(Vh[off]);
    __syncthreads();
#pragma unroll
    for (int q = 0; q < 4; ++q) {
      const f32x4 a = *(const f32x4*)&ek[q][tdk];
      const f32x4 vx = *(const f32x4*)&vv[q][tdv];
      U[0] += a[0] * vx;
      U[1] += a[1] * vx;
      U[2] += a[2] * vx;
      U[3] += a[3] * vx;
    }
    __syncthreads();
  }
  float* Ub = Upart + (long)(bh * 8 + chunk) * 4096;
#pragma unroll
  for (int i = 0; i < 4; ++i) *(f32x4*)&Ub[(tdk + i) * 64 + tdv] = U[i];
  sred[t] = myS;
  __syncthreads();
  if (t < 64) {
    const float s = sred[t] + sred[t + 64] + sred[t + 128] + sred[t + 192];
    Spart[(long)(bh * 8 + chunk) * 64 + t] = s;
  }
}

__global__ __launch_bounds__(256)
void ctx_reduce(const float* __restrict__ Upart, const float* __restrict__ Spart,
                float* __restrict__ ctx) {
  const int bh = blockIdx.x;
  const int t = threadIdx.x;
  const int tdk = (t & 15) * 4, tdv = (t >> 4) * 4;
  __shared__ float S[64];
  if (t < 64) {
    float s = 0.f;
#pragma unroll
    for (int c = 0; c < 8; ++c) s += Spart[(long)(bh * 8 + c) * 64 + t];
    S[t] = s;
  }
  __syncthreads();
#pragma unroll
  for (int i = 0; i < 4; ++i) {
    const int dk = tdk + i;
    f32x4 u = {};
#pragma unroll
    for (int c = 0; c < 8; ++c)
      u += *(const f32x4*)&Upart[(long)(bh * 8 + c) * 4096 + dk * 64 + tdv];
    u *= (1.f / S[dk]);
    *(f32x4*)&ctx[(long)bh * 4096 + dk * 64 + tdv] = u;
  }
}

// ---------------------------------------------------------------- G matrix
// Gt[b][co][h*64+dk] = sum_dv ctx[b,h,dk,dv] * Wp[co, h*64+dv]   (bf16 out)
__global__ __launch_bounds__(256, 2)
void gstack(const float* __restrict__ ctx, const float* __restrict__ Wp,
            __bf16* __restrict__ Gt) {
  const int cc = blockIdx.x, h = blockIdx.y, b = blockIdx.z;
  const int t = threadIdx.x, lane = t & 63, w = t >> 6;
  const int co0 = cc * 192;
  __shared__ __align__(16) float wf[192 * 64];  // 48 KB

#pragma unroll
  for (int i = 0; i < 12; ++i) {
    const int flat = i * 256 + t;
    const int r = flat >> 4, c4 = flat & 15;
    const f32x4 vsrc = *(const f32x4*)&Wp[(long)(co0 + r) * 768 + h * 64 + c4 * 4];
    *(f32x4*)&wf[r * 64 + c4 * 4] = vsrc;
  }

  f32x4 cx[16];
  const float* crow = ctx + ((long)(b * 12 + h) * 64 + lane) * 64;
#pragma unroll
  for (int j = 0; j < 16; ++j) cx[j] = *(const f32x4*)&crow[j * 4];

  __syncthreads();

  __bf16* gout = Gt + ((long)(b * 768 + co0 + w * 48) * 768) + h * 64 + lane;
  for (int co = 0; co < 48; ++co) {
    const float* wrow = &wf[(w * 48 + co) * 64];
    f32x4 acc = {};
#pragma unroll
    for (int j = 0; j < 16; ++j) acc += cx[j] * *(const f32x4*)&wrow[j * 4];
    const float s = acc[0] + acc[1] + acc[2] + acc[3];
    gout[(long)co * 768] = (__bf16)s;
  }
}

// ---------------------------------------------------------------- launch
extern "C" void kernel_launch(void* const* d_in, const int* in_sizes, int n_in,
                              void* d_out, int out_size, void* d_ws, size_t ws_size,
                              hipStream_t stream) {
  (void)in_sizes; (void)n_in; (void)out_size; (void)ws_size;
  const float* q = (const float*)d_in[0];
  const float* k = (const float*)d_in[1];
  const float* v = (const float*)d_in[2];
  const float* Wq = (const float*)d_in[3];
  const float* Wk = (const float*)d_in[4];
  const float* Wv = (const float*)d_in[5];
  const float* Wp = (const float*)d_in[6];
  const float* bp = (const float*)d_in[7];
  float* out = (float*)d_out;

  const long XE = 32768L * 768L;
  const long WE = 768L * 768L;

  // ws layout (~285 MB):
  char* ws = (char*)d_ws;
  __bf16* Kb = (__bf16*)ws;                              // XE bf16 (cast k)
  __bf16* Vb = Kb + XE;                                  // XE bf16 (cast v)
  __bf16* Qb = Vb + XE;                                  // XE bf16 (cast q)
  __bf16* Khb = Qb + XE;                                 // XE bf16
  __bf16* Vhb = Khb + XE;                                // XE bf16
  __bf16* Wb = Vhb + XE;                                 // 4*WE bf16: Wk,Wv,(spare),WqT
  __bf16* Gt = Wb + 4 * WE;                              // 8*WE bf16
  __bf16* Mt = Gt + 8 * WE;                              // 8*WE bf16
  float* Upart = (float*)(Mt + 8 * WE);                  // 96*8*4096 f32
  float* Spart = Upart + 96L * 8 * 4096;                 // 96*8*64 f32
  float* ctx = Spart + 96L * 8 * 64;                     // 96*4096 f32

  // 1) weight casts (tiny) + activation casts (one z=3 streaming dispatch)
  cast_kernel<<<576, 256, 0, stream>>>(Wk, Wb + 0 * WE, WE);
  cast_kernel<<<576, 256, 0, stream>>>(Wv, Wb + 1 * WE, WE);
  transpose_cast<<<dim3(24, 24), dim3(32, 8), 0, stream>>>(Wq, Wb + 3 * WE);  // WqT
  cast3_kernel<<<dim3(24576, 3), 256, 0, stream>>>(k, v, q, Kb, Vb, Qb);

  // 2) K/V projections (z=2): Kh = Kb@Wk^T, Vh = Vb@Wv^T  (bf16 out)
  gemm_bt<<<dim3(6, 256, 2), 256, 0, stream>>>(Kb, Wb, Khb, nullptr, nullptr,
                                               XE, WE, XE, 0);

  // 3) softmax-weighted context
  ctx_partial<<<dim3(8, 96), 256, 0, stream>>>((const __hip_bfloat16*)Khb,
                                               (const __hip_bfloat16*)Vhb, Upart, Spart);
  ctx_reduce<<<96, 256, 0, stream>>>(Upart, Spart, ctx);

  // 4) Gt[b] = (ctx @ Wp-blocks)^T   (bf16, per batch; fp32 Wp direct)
  gstack<<<dim3(4, 12, 8), 256, 0, stream>>>(ctx, Wp, Gt);

  // 5) Mt[b] : out[m=co, n=ci] = sum_k Gt[co,k] * WqT[ci,k]
  gemm_bt<<<dim3(6, 6, 8), 256, 0, stream>>>(Gt, Wb + 3 * WE, Mt, nullptr,
                                             nullptr, WE, 0, WE, 0);

  // 6) out[b] = Qb[b] @ Mt[b]^T + bp  (fp32 out)
  gemm_bt<<<dim3(6, 256, 1), 256, 0, stream>>>(Qb, Mt, nullptr, out,
                                               bp, 0, 0, 0, WE);
}

// Round 8
// 364.991 us; speedup vs baseline: 1.2055x; 1.0337x over previous
//
#include <hip/hip_runtime.h>
#include <hip/hip_bf16.h>

// FactorAtt (CoaT) fused pipeline v7, MI355X/gfx950.
// B=8, N=4096, C=768, H=12, D=64.  M_tot = B*N = 32768.
//
// Math: out[b] = q[b] @ M[b] + bp, where
//   Kh = k @ Wk^T (bf16), Vh = v @ Wv^T
//   ctx[b,h,dk,dv] = sum_n softmax_n(Kh)[n,dk] * Vh[n,dv]
//   Gt[b][co][h*64+dk] = sum_dv ctx[b,h,dk,dv] * Wp[co, h*64+dv]
//   Mt[b][co][ci] = sum_kk Gt[b][co][kk] * Wq[kk][ci]
//   out[b][n,co] = sum_ci q[b][n,ci] * Mt[b][co,ci] + bp[co]
// v7: gemm_bt BK 32->64 (halves barrier-drain count; 12 K-steps) +
// XOR chunk swizzle both-sides (T2/rule21: linear LDS dest, inverse-swizzled
// global source, swizzled frag read) to kill the 8/16-way ds_read conflict.
// Single-buffered 32KB LDS (occupancy preserved — v4/v5 lesson).

typedef __bf16 bf16x8 __attribute__((ext_vector_type(8)));
typedef __bf16 bf16x4 __attribute__((ext_vector_type(4)));
typedef float f32x4 __attribute__((ext_vector_type(4)));

#define GLOAD_LDS16(g, l)                                                        \
  __builtin_amdgcn_global_load_lds(                                              \
      (const __attribute__((address_space(1))) void*)(g),                        \
      (__attribute__((address_space(3))) void*)(l), 16, 0, 0)

__device__ __forceinline__ float bf2f(__hip_bfloat16 h) { return __bfloat162float(h); }

// ---------------------------------------------------------------- casts
__global__ void cast_kernel(const float* __restrict__ src,
                            __bf16* __restrict__ dst, long n) {
  long i = ((long)blockIdx.x * blockDim.x + threadIdx.x) * 4;
  if (i + 3 < n) {
    const float4 f = *(const float4*)(src + i);
    bf16x4 u = {(__bf16)f.x, (__bf16)f.y, (__bf16)f.z, (__bf16)f.w};
    *(bf16x4*)(dst + i) = u;
  }
}

// three tensors of exactly XE elements each
__global__ void cast3_kernel(const float* __restrict__ s0, const float* __restrict__ s1,
                             const float* __restrict__ s2,
                             __bf16* __restrict__ d0, __bf16* __restrict__ d1,
                             __bf16* __restrict__ d2) {
  const float* src = blockIdx.y == 0 ? s0 : (blockIdx.y == 1 ? s1 : s2);
  __bf16* dst = blockIdx.y == 0 ? d0 : (blockIdx.y == 1 ? d1 : d2);
  const long i = ((long)blockIdx.x * blockDim.x + threadIdx.x) * 4;
  const float4 f = *(const float4*)(src + i);
  bf16x4 u = {(__bf16)f.x, (__bf16)f.y, (__bf16)f.z, (__bf16)f.w};
  *(bf16x4*)(dst + i) = u;
}

// dst[ci][kk] = src[kk][ci]  (768x768, fp32 -> bf16)
__global__ void transpose_cast(const float* __restrict__ src,
                               __bf16* __restrict__ dst) {
  __shared__ float tile[32][33];
  const int bx = blockIdx.x * 32, by = blockIdx.y * 32;
  const int tx = threadIdx.x, ty = threadIdx.y;  // 32 x 8
#pragma unroll
  for (int j = 0; j < 32; j += 8)
    tile[ty + j][tx] = src[(long)(bx + ty + j) * 768 + by + tx];
  __syncthreads();
#pragma unroll
  for (int j = 0; j < 32; j += 8)
    dst[(long)(by + ty + j) * 768 + bx + tx] = (__bf16)tile[tx][ty + j];
}

// ---------------------------------------------------------------- GEMM (B^T form)
// out[m,n] = sum_k A[m,k] * Bt[n,k];  K=768, tiles 128x128, BK=64, 4 waves.
// Single-buffered LDS (2 x 16KB), 2 barriers per K-step, 12 K-steps.
// LDS tiles [128][64] bf16 with chunk swizzle: phys16B chunk = logical ^ (row&7).
__global__ __launch_bounds__(256, 2)
void gemm_bt(const __bf16* __restrict__ Abase,
             const __bf16* __restrict__ Btbase,
             __bf16* __restrict__ outBbase,
             float* __restrict__ outF,
             const float* __restrict__ bias,
             long sAz, long sBz, long sOz, long sBbatch) {
  constexpr int K = 768;
  const int tid = threadIdx.x;
  const int lane = tid & 63;
  const int w = tid >> 6;
  const int wr = (w >> 1) * 64;
  const int wc = (w & 1) * 64;

  // bijective XCD-chunked swizzle (m204)
  long flat = ((long)blockIdx.z * gridDim.y + blockIdx.y) * gridDim.x + blockIdx.x;
  const long total = (long)gridDim.x * gridDim.y * gridDim.z;
  if ((total & 7) == 0) {
    flat = (flat & 7) * (total >> 3) + (flat >> 3);
  }
  const int bx = (int)(flat % gridDim.x);
  const long rem = flat / gridDim.x;
  const int by = (int)(rem % gridDim.y);
  const int bz = (int)(rem / gridDim.y);

  const int z = bz;
  const int m0 = by * 128;
  const int n0 = bx * 128;

  const __bf16* A = Abase + (long)z * sAz;
  const __bf16* Bt = Btbase + (long)z * sBz + (long)(m0 >> 12) * sBbatch;

  __shared__ __align__(16) __bf16 As[128 * 64];  // 16 KB
  __shared__ __align__(16) __bf16 Bs[128 * 64];  // 16 KB

  f32x4 acc[4][4] = {};

  // staging: per issue p (0..3), rows p*32 + w*8 + (lane>>3); 8 x 16B chunks/row.
  // Global source chunk = (lane&7) ^ (lane>>3)  (inverse swizzle, row&7 == lane>>3).
  // LDS dest linear: base + lane*16B.
  const int ro = lane >> 3;              // row within 8-row group
  const int gck = (lane & 7) ^ ro;       // logical chunk to fetch
  const __bf16* gA = A + (long)(m0 + w * 8 + ro) * K + gck * 8;
  const __bf16* gB = Bt + (long)(n0 + w * 8 + ro) * K + gck * 8;

  const int rsel = lane & 15;
  const int r7 = rsel & 7;               // (frag row) & 7
  const int cseg = lane >> 4;            // 0..3: logical chunk within kk-half

  for (int k0 = 0; k0 < K; k0 += 64) {
#pragma unroll
    for (int p = 0; p < 4; ++p) {
      GLOAD_LDS16(gA + k0 + (long)p * 32 * K, &As[(p * 32 + w * 8) * 64]);
      GLOAD_LDS16(gB + k0 + (long)p * 32 * K, &Bs[(p * 32 + w * 8) * 64]);
    }
    __syncthreads();

#pragma unroll
    for (int kk = 0; kk < 2; ++kk) {
      const int ckl = kk * 4 + cseg;     // logical chunk 0..7
      bf16x8 af[4], bfr[4];
#pragma unroll
      for (int i = 0; i < 4; ++i) {
        const int rowa = wr + i * 16 + rsel;
        const int rowb = wc + i * 16 + rsel;
        af[i] = *(const bf16x8*)&As[rowa * 64 + ((ckl ^ r7) << 3)];
        bfr[i] = *(const bf16x8*)&Bs[rowb * 64 + ((ckl ^ r7) << 3)];
      }
#pragma unroll
      for (int i = 0; i < 4; ++i)
#pragma unroll
        for (int j = 0; j < 4; ++j)
          acc[i][j] = __builtin_amdgcn_mfma_f32_16x16x32_bf16(af[i], bfr[j], acc[i][j], 0, 0, 0);
    }
    __syncthreads();
  }

  // C/D layout (m89): col = lane&15, row = (lane>>4)*4 + r
  const int r0 = (lane >> 4) * 4;
  if (outF == nullptr) {
    __bf16* outp = outBbase + (long)z * sOz;
#pragma unroll
    for (int i = 0; i < 4; ++i) {
      const int row = m0 + wr + i * 16 + r0;
#pragma unroll
      for (int j = 0; j < 4; ++j) {
        const int col = n0 + wc + j * 16 + rsel;
#pragma unroll
        for (int r = 0; r < 4; ++r)
          outp[(long)(row + r) * 768 + col] = (__bf16)acc[i][j][r];
      }
    }
  } else {
#pragma unroll
    for (int i = 0; i < 4; ++i) {
      const int row = m0 + wr + i * 16 + r0;
#pragma unroll
      for (int j = 0; j < 4; ++j) {
        const int col = n0 + wc + j * 16 + rsel;
        const float bv = bias[col];
#pragma unroll
        for (int r = 0; r < 4; ++r)
          outF[(long)(row + r) * 768 + col] = acc[i][j][r] + bv;
      }
    }
  }
}

// ---------------------------------------------------------------- ctx partials
__global__ __launch_bounds__(256)
void ctx_partial(const __hip_bfloat16* __restrict__ Kh,
                 const __hip_bfloat16* __restrict__ Vh,
                 float* __restrict__ Upart, float* __restrict__ Spart) {
  const int bh = blockIdx.y, chunk = blockIdx.x;
  const int b = bh / 12, h = bh % 12;
  const int t = threadIdx.x;
  const int rr = t >> 6, d = t & 63;
  const int tdk = (t & 15) * 4, tdv = (t >> 4) * 4;
  __shared__ float ek[4][64];
  __shared__ float vv[4][64];
  __shared__ float sred[256];
  f32x4 U[4] = {};
  float myS = 0.f;
  const long base = ((long)b * 4096 + (long)chunk * 512) * 768 + h * 64 + d;
  for (int r4 = 0; r4 < 128; ++r4) {
    const long off = base + (long)(r4 * 4 + rr) * 768;
    const float e = __expf(bf2f(Kh[off]));
    ek[rr][d] = e;
    myS += e;
    vv[rr][d] = bf2f(Vh[off]);
    __syncthreads();
#pragma unroll
    for (int q = 0; q < 4; ++q) {
      const f32x4 a = *(const f32x4*)&ek[q][tdk];
      const f32x4 vx = *(const f32x4*)&vv[q][tdv];
      U[0] += a[0] * vx;
      U[1] += a[1] * vx;
      U[2] += a[2] * vx;
      U[3] += a[3] * vx;
    }
    __syncthreads();
  }
  float* Ub = Upart + (long)(bh * 8 + chunk) * 4096;
#pragma unroll
  for (int i = 0; i < 4; ++i) *(f32x4*)&Ub[(tdk + i) * 64 + tdv] = U[i];
  sred[t] = myS;
  __syncthreads();
  if (t < 64) {
    const float s = sred[t] + sred[t + 64] + sred[t + 128] + sred[t + 192];
    Spart[(long)(bh * 8 + chunk) * 64 + t] = s;
  }
}

__global__ __launch_bounds__(256)
void ctx_reduce(const float* __restrict__ Upart, const float* __restrict__ Spart,
                float* __restrict__ ctx) {
  const int bh = blockIdx.x;
  const int t = threadIdx.x;
  const int tdk = (t & 15) * 4, tdv = (t >> 4) * 4;
  __shared__ float S[64];
  if (t < 64) {
    float s = 0.f;
#pragma unroll
    for (int c = 0; c < 8; ++c) s += Spart[(long)(bh * 8 + c) * 64 + t];
    S[t] = s;
  }
  __syncthreads();
#pragma unroll
  for (int i = 0; i < 4; ++i) {
    const int dk = tdk + i;
    f32x4 u = {};
#pragma unroll
    for (int c = 0; c < 8; ++c)
      u += *(const f32x4*)&Upart[(long)(bh * 8 + c) * 4096 + dk * 64 + tdv];
    u *= (1.f / S[dk]);
    *(f32x4*)&ctx[(long)bh * 4096 + dk * 64 + tdv] = u;
  }
}

// ---------------------------------------------------------------- G matrix
// Gt[b][co][h*64+dk] = sum_dv ctx[b,h,dk,dv] * Wp[co, h*64+dv]   (bf16 out)
__global__ __launch_bounds__(256, 2)
void gstack(const float* __restrict__ ctx, const float* __restrict__ Wp,
            __bf16* __restrict__ Gt) {
  const int cc = blockIdx.x, h = blockIdx.y, b = blockIdx.z;
  const int t = threadIdx.x, lane = t & 63, w = t >> 6;
  const int co0 = cc * 192;
  __shared__ __align__(16) float wf[192 * 64];  // 48 KB

#pragma unroll
  for (int i = 0; i < 12; ++i) {
    const int flat = i * 256 + t;
    const int r = flat >> 4, c4 = flat & 15;
    const f32x4 vsrc = *(const f32x4*)&Wp[(long)(co0 + r) * 768 + h * 64 + c4 * 4];
    *(f32x4*)&wf[r * 64 + c4 * 4] = vsrc;
  }

  f32x4 cx[16];
  const float* crow = ctx + ((long)(b * 12 + h) * 64 + lane) * 64;
#pragma unroll
  for (int j = 0; j < 16; ++j) cx[j] = *(const f32x4*)&crow[j * 4];

  __syncthreads();

  __bf16* gout = Gt + ((long)(b * 768 + co0 + w * 48) * 768) + h * 64 + lane;
  for (int co = 0; co < 48; ++co) {
    const float* wrow = &wf[(w * 48 + co) * 64];
    f32x4 acc = {};
#pragma unroll
    for (int j = 0; j < 16; ++j) acc += cx[j] * *(const f32x4*)&wrow[j * 4];
    const float s = acc[0] + acc[1] + acc[2] + acc[3];
    gout[(long)co * 768] = (__bf16)s;
  }
}

// ---------------------------------------------------------------- launch
extern "C" void kernel_launch(void* const* d_in, const int* in_sizes, int n_in,
                              void* d_out, int out_size, void* d_ws, size_t ws_size,
                              hipStream_t stream) {
  (void)in_sizes; (void)n_in; (void)out_size; (void)ws_size;
  const float* q = (const float*)d_in[0];
  const float* k = (const float*)d_in[1];
  const float* v = (const float*)d_in[2];
  const float* Wq = (const float*)d_in[3];
  const float* Wk = (const float*)d_in[4];
  const float* Wv = (const float*)d_in[5];
  const float* Wp = (const float*)d_in[6];
  const float* bp = (const float*)d_in[7];
  float* out = (float*)d_out;

  const long XE = 32768L * 768L;
  const long WE = 768L * 768L;

  char* ws = (char*)d_ws;
  __bf16* Kb = (__bf16*)ws;                              // XE bf16 (cast k)
  __bf16* Vb = Kb + XE;                                  // XE bf16 (cast v)
  __bf16* Qb = Vb + XE;                                  // XE bf16 (cast q)
  __bf16* Khb = Qb + XE;                                 // XE bf16
  __bf16* Vhb = Khb + XE;                                // XE bf16
  __bf16* Wb = Vhb + XE;                                 // 4*WE bf16: Wk,Wv,(spare),WqT
  __bf16* Gt = Wb + 4 * WE;                              // 8*WE bf16
  __bf16* Mt = Gt + 8 * WE;                              // 8*WE bf16
  float* Upart = (float*)(Mt + 8 * WE);                  // 96*8*4096 f32
  float* Spart = Upart + 96L * 8 * 4096;                 // 96*8*64 f32
  float* ctx = Spart + 96L * 8 * 64;                     // 96*4096 f32

  // 1) weight casts (tiny) + activation casts (one z=3 streaming dispatch)
  cast_kernel<<<576, 256, 0, stream>>>(Wk, Wb + 0 * WE, WE);
  cast_kernel<<<576, 256, 0, stream>>>(Wv, Wb + 1 * WE, WE);
  transpose_cast<<<dim3(24, 24), dim3(32, 8), 0, stream>>>(Wq, Wb + 3 * WE);  // WqT
  cast3_kernel<<<dim3(24576, 3), 256, 0, stream>>>(k, v, q, Kb, Vb, Qb);

  // 2) K/V projections (z=2): Kh = Kb@Wk^T, Vh = Vb@Wv^T  (bf16 out)
  gemm_bt<<<dim3(6, 256, 2), 256, 0, stream>>>(Kb, Wb, Khb, nullptr, nullptr,
                                               XE, WE, XE, 0);

  // 3) softmax-weighted context
  ctx_partial<<<dim3(8, 96), 256, 0, stream>>>((const __hip_bfloat16*)Khb,
                                               (const __hip_bfloat16*)Vhb, Upart, Spart);
  ctx_reduce<<<96, 256, 0, stream>>>(Upart, Spart, ctx);

  // 4) Gt[b] = (ctx @ Wp-blocks)^T   (bf16, per batch; fp32 Wp direct)
  gstack<<<dim3(4, 12, 8), 256, 0, stream>>>(ctx, Wp, Gt);

  // 5) Mt[b] : out[m=co, n=ci] = sum_k Gt[co,k] * WqT[ci,k]
  gemm_bt<<<dim3(6, 6, 8), 256, 0, stream>>>(Gt, Wb + 3 * WE, Mt, nullptr,
                                             nullptr, WE, 0, WE, 0);

  // 6) out[b] = Qb[b] @ Mt[b]^T + bp  (fp32 out)
  gemm_bt<<<dim3(6, 256, 1), 256, 0, stream>>>(Qb, Mt, nullptr, out,
                                               bp, 0, 0, 0, WE);
}